// Round 3
// baseline (877.936 us; speedup 1.0000x reference)
//
#include <hip/hip_runtime.h>

// ---------------------------------------------------------------------------
// Bahdanau attention, B=64 L=1024 D=H=U=1024, fp32 in/out.
//   score[b,l] = sum_u tanh( (feat[b,l,:]@W1[:,u]) + b1[u] + (hid[b,:]@W2[:,u]) + b2[u] ) * V[u]
//   w = softmax_L(score)   (bV dropped: softmax shift-invariant)
//   ctx[b,:] = sum_l w[b,l] * feat[b,l,:]
// Big GEMM done in bf16 MFMA (no fp32 MFMA on CDNA4), fused tanh*V epilogue.
// ---------------------------------------------------------------------------

#define GLD16(g, l) __builtin_amdgcn_global_load_lds(                          \
    (const __attribute__((address_space(1))) void*)(g),                        \
    (__attribute__((address_space(3))) void*)(l), 16, 0, 0)

typedef __attribute__((ext_vector_type(8))) short bf16x8;
typedef __attribute__((ext_vector_type(4))) float f32x4;
typedef __attribute__((ext_vector_type(8))) unsigned short us8;

__device__ __forceinline__ unsigned short f2bf(float f) {
  unsigned u = __float_as_uint(f);            // RNE fp32->bf16
  return (unsigned short)((u + 0x7FFFu + ((u >> 16) & 1u)) >> 16);
}

// K1: ph[b][u] = hidden[b,:] @ W2[:,u] + b2[u].  grid(16,64), 256 thr.
__global__ __launch_bounds__(256) void projh_k(
    const float* __restrict__ hidden, const float* __restrict__ W2,
    const float* __restrict__ b2, float* __restrict__ ph) {
  __shared__ float hs[1024];
  __shared__ float red[4][64];
  const int b = blockIdx.y, ch = blockIdx.x, t = threadIdx.x;
#pragma unroll
  for (int j = 0; j < 4; ++j) hs[t + j * 256] = hidden[b * 1024 + t + j * 256];
  __syncthreads();
  const int ul = t & 63, hq = t >> 6;
  const int u = ch * 64 + ul;
  float acc = 0.f;
#pragma unroll 4
  for (int i = 0; i < 256; ++i) {
    int h = hq * 256 + i;
    acc += hs[h] * W2[(size_t)h * 1024 + u];
  }
  red[hq][ul] = acc;
  __syncthreads();
  if (t < 64) {
    float s = red[0][t] + red[1][t] + red[2][t] + red[3][t] + b2[ch * 64 + t];
    ph[b * 1024 + ch * 64 + t] = s;
  }
}

// K2: W1[d][u] -> tiled/transposed/swizzled bf16 for global_load_lds staging.
// Tile (nb,ks): 128 cols (u) x 32 k (d), layout Bs[col][k] with
// short_off = col*32 + (k ^ ((col&3)<<3))  (16B-chunk XOR swizzle).
// grid(512), 256 thr: one 8-element 16B chunk per thread.
__global__ __launch_bounds__(256) void w1tile_k(
    const float* __restrict__ W1, unsigned short* __restrict__ w1t) {
  const int i = blockIdx.x * 256 + threadIdx.x;  // 131072 total
  const int u = i >> 7, c = i & 127;
  const int ks = c >> 2, kg = c & 3;
  const int col = u & 127, nb = u >> 7;
  us8 pk;
#pragma unroll
  for (int j = 0; j < 8; ++j) {
    int d = ks * 32 + kg * 8 + j;
    pk[j] = f2bf(W1[(size_t)d * 1024 + u]);
  }
  size_t off = (size_t)(nb * 32 + ks) * 4096 + col * 32 +
               ((unsigned)(kg ^ (col & 3)) << 3);
  *(us8*)(&w1t[off]) = pk;
}

// K3: fused score GEMM. 128x128 tile, BK=32, 4 waves (2x2), 4x4 16x16x32 frags.
// Double-buffered LDS, one barrier per K-step. A: fp32->bf16 reg-staged,
// XOR-swizzled ds_write. B: global_load_lds(16) from pre-swizzled w1t.
// Epilogue: tanh(acc + b1 + ph) * V[u], reduce over the 128-col panel ->
// partial[nb][m].  grid(nb=8, mb=512), 256 thr.
__global__ __launch_bounds__(256) void score_gemm(
    const float* __restrict__ feat, const unsigned short* __restrict__ w1t,
    const float* __restrict__ b1, const float* __restrict__ ph,
    const float* __restrict__ V, float* __restrict__ partial) {
  __shared__ unsigned short As[2][128 * 32];
  __shared__ unsigned short Bs[2][128 * 32];
  __shared__ float phb1_s[128], vs_s[128];
  __shared__ float red2[2][128];

  const int nb = blockIdx.x;
  const int m_base = blockIdx.y * 128;
  const int b = m_base >> 10;   // BM=128 divides L=1024: one b per block
  const int tid = threadIdx.x;
  const int lane = tid & 63;
  const int w = tid >> 6, wr = w >> 1, wc = w & 1;

  if (tid < 128) {
    int u = nb * 128 + tid;
    phb1_s[tid] = b1[u] + ph[b * 1024 + u];
    vs_s[tid] = V[u];
  }

  f32x4 acc[4][4];
#pragma unroll
  for (int mi = 0; mi < 4; ++mi)
#pragma unroll
    for (int ni = 0; ni < 4; ++ni) acc[mi][ni] = (f32x4){0.f, 0.f, 0.f, 0.f};

  const int srow = tid >> 3;  // 0..31, + p*32
  const int scg = tid & 7;    // 4-float group within row
  const float* fbase = feat + (size_t)m_base * 1024 + scg * 4;
  const unsigned short* wpanel = w1t + (size_t)nb * 131072;

  // prologue: stage ks=0 into buf 0
  {
#pragma unroll
    for (int j = 0; j < 2; ++j) {
      int cch = w * 2 + j;
      GLD16(wpanel + cch * 512 + lane * 8, &Bs[0][cch * 512]);
    }
#pragma unroll
    for (int p = 0; p < 4; ++p) {
      int row = p * 32 + srow;
      float4 v = *(const float4*)(fbase + (size_t)row * 1024);
      int off = row * 32 + ((scg * 4) ^ ((row & 3) << 3));
      unsigned a0 = f2bf(v.x) | ((unsigned)f2bf(v.y) << 16);
      unsigned a1 = f2bf(v.z) | ((unsigned)f2bf(v.w) << 16);
      *(uint2*)(&As[0][off]) = make_uint2(a0, a1);
    }
  }
  __syncthreads();

  const int kg = lane >> 4;
  int aoff[4], boff[4];
#pragma unroll
  for (int mi = 0; mi < 4; ++mi) {
    int row = wr * 64 + mi * 16 + (lane & 15);
    aoff[mi] = row * 32 + ((kg * 8) ^ ((row & 3) << 3));
  }
#pragma unroll
  for (int ni = 0; ni < 4; ++ni) {
    int col = wc * 64 + ni * 16 + (lane & 15);
    boff[ni] = col * 32 + ((kg * 8) ^ ((col & 3) << 3));
  }

  int cur = 0;
  for (int ks = 0; ks < 32; ++ks) {
    const int nxt = cur ^ 1;
    const bool more = (ks + 1) < 32;
    float4 av[4];
    if (more) {
      const unsigned short* tsrc = wpanel + (size_t)(ks + 1) * 4096;
#pragma unroll
      for (int j = 0; j < 2; ++j) {
        int cch = w * 2 + j;
        GLD16(tsrc + cch * 512 + lane * 8, &Bs[nxt][cch * 512]);
      }
#pragma unroll
      for (int p = 0; p < 4; ++p) {
        int row = p * 32 + srow;
        av[p] = *(const float4*)(fbase + (size_t)row * 1024 + (ks + 1) * 32);
      }
    }
    bf16x8 afr[4], bfr[4];
#pragma unroll
    for (int mi = 0; mi < 4; ++mi)
      afr[mi] = *(const bf16x8*)(&As[cur][aoff[mi]]);
#pragma unroll
    for (int ni = 0; ni < 4; ++ni)
      bfr[ni] = *(const bf16x8*)(&Bs[cur][boff[ni]]);
#pragma unroll
    for (int mi = 0; mi < 4; ++mi)
#pragma unroll
      for (int ni = 0; ni < 4; ++ni)
        acc[mi][ni] = __builtin_amdgcn_mfma_f32_16x16x32_bf16(
            afr[mi], bfr[ni], acc[mi][ni], 0, 0, 0);
    if (more) {
#pragma unroll
      for (int p = 0; p < 4; ++p) {
        int row = p * 32 + srow;
        int off = row * 32 + ((scg * 4) ^ ((row & 3) << 3));
        unsigned a0 = f2bf(av[p].x) | ((unsigned)f2bf(av[p].y) << 16);
        unsigned a1 = f2bf(av[p].z) | ((unsigned)f2bf(av[p].w) << 16);
        *(uint2*)(&As[nxt][off]) = make_uint2(a0, a1);
      }
    }
    __syncthreads();
    cur = nxt;
  }

  // epilogue: tanh(acc + ph + b1) * V, reduce over this block's 128 cols.
  // C/D layout: col = lane&15, row = (lane>>4)*4 + r  [m89-verified]
  float rs[4][4];
#pragma unroll
  for (int mi = 0; mi < 4; ++mi)
#pragma unroll
    for (int r = 0; r < 4; ++r) rs[mi][r] = 0.f;
#pragma unroll
  for (int ni = 0; ni < 4; ++ni) {
    int ucol = wc * 64 + ni * 16 + (lane & 15);
    float pv = phb1_s[ucol], vv = vs_s[ucol];
#pragma unroll
    for (int mi = 0; mi < 4; ++mi)
#pragma unroll
      for (int r = 0; r < 4; ++r)
        rs[mi][r] += tanhf(acc[mi][ni][r] + pv) * vv;
  }
#pragma unroll
  for (int mi = 0; mi < 4; ++mi)
#pragma unroll
    for (int r = 0; r < 4; ++r) {
      float x = rs[mi][r];
      x += __shfl_xor(x, 1);
      x += __shfl_xor(x, 2);
      x += __shfl_xor(x, 4);
      x += __shfl_xor(x, 8);
      rs[mi][r] = x;
    }
  if ((lane & 15) == 0) {
    int rq = lane >> 4;
#pragma unroll
    for (int mi = 0; mi < 4; ++mi)
#pragma unroll
      for (int r = 0; r < 4; ++r)
        red2[wc][wr * 64 + mi * 16 + rq * 4 + r] = rs[mi][r];
  }
  __syncthreads();
  if (tid < 128)
    partial[(size_t)nb * 65536 + m_base + tid] = red2[0][tid] + red2[1][tid];
}

// K4: softmax over L per b.  grid(64), 256 thr x 4 l each.
__global__ __launch_bounds__(256) void softmax_k(
    const float* __restrict__ partial, float* __restrict__ wout) {
  const int b = blockIdx.x, t = threadIdx.x;
  const int lane = t & 63, w = t >> 6;
  __shared__ float smax[4], ssum[4];
  float s[4];
#pragma unroll
  for (int j = 0; j < 4; ++j) {
    int l = t + j * 256;
    float v = 0.f;
#pragma unroll
    for (int nb = 0; nb < 8; ++nb) v += partial[(size_t)nb * 65536 + b * 1024 + l];
    s[j] = v;
  }
  float mx = fmaxf(fmaxf(s[0], s[1]), fmaxf(s[2], s[3]));
#pragma unroll
  for (int off = 1; off < 64; off <<= 1) mx = fmaxf(mx, __shfl_xor(mx, off));
  if (lane == 0) smax[w] = mx;
  __syncthreads();
  mx = fmaxf(fmaxf(smax[0], smax[1]), fmaxf(smax[2], smax[3]));
  float e[4], sum = 0.f;
#pragma unroll
  for (int j = 0; j < 4; ++j) { e[j] = expf(s[j] - mx); sum += e[j]; }
#pragma unroll
  for (int off = 1; off < 64; off <<= 1) sum += __shfl_xor(sum, off);
  if (lane == 0) ssum[w] = sum;
  __syncthreads();
  const float inv = 1.f / (ssum[0] + ssum[1] + ssum[2] + ssum[3]);
#pragma unroll
  for (int j = 0; j < 4; ++j) wout[b * 1024 + t + j * 256] = e[j] * inv;
}

// K5: ctx[b][d] = sum_l w[b][l] * feat[b][l][d].  grid(8,64), 256 thr:
// 128 d's x 2 l-halves, LDS-staged weights, LDS combine.
__global__ __launch_bounds__(256) void context_k(
    const float* __restrict__ feat, const float* __restrict__ wts,
    float* __restrict__ ctx) {
  __shared__ float wsm[1024];
  __shared__ float red[128];
  const int b = blockIdx.y, ch = blockIdx.x, t = threadIdx.x;
#pragma unroll
  for (int j = 0; j < 4; ++j) wsm[t + j * 256] = wts[b * 1024 + t + j * 256];
  __syncthreads();
  const int dl = t & 127, lh = t >> 7;
  const int d = ch * 128 + dl;
  const float* fb = feat + (size_t)b * 1048576 + d;
  float acc = 0.f;
#pragma unroll 4
  for (int l = lh * 512; l < lh * 512 + 512; ++l)
    acc += wsm[l] * fb[(size_t)l * 1024];
  if (lh == 0) red[dl] = acc;
  __syncthreads();
  if (lh == 1) ctx[b * 1024 + d] = red[dl] + acc;
}

extern "C" void kernel_launch(void* const* d_in, const int* in_sizes, int n_in,
                              void* d_out, int out_size, void* d_ws,
                              size_t ws_size, hipStream_t stream) {
  const float* feat = (const float*)d_in[0];    // [64][1024][1024]
  const float* hidden = (const float*)d_in[1];  // [64][1024]
  const float* W1 = (const float*)d_in[2];      // [1024][1024]
  const float* b1 = (const float*)d_in[3];      // [1024]
  const float* W2 = (const float*)d_in[4];      // [1024][1024]
  const float* b2 = (const float*)d_in[5];      // [1024]
  const float* V = (const float*)d_in[6];       // [1024]
  // d_in[7] = bV: unused (softmax is shift-invariant)
  float* out = (float*)d_out;  // [0,65536): context  [65536,131072): weights

  // workspace layout (~4.25 MB): ph | partial[8][65536] | w1t bf16 tiled
  float* ph = (float*)d_ws;
  float* partial = ph + 65536;
  unsigned short* w1t = (unsigned short*)(partial + 524288);

  hipLaunchKernelGGL(projh_k, dim3(16, 64), dim3(256), 0, stream, hidden, W2, b2, ph);
  hipLaunchKernelGGL(w1tile_k, dim3(512), dim3(256), 0, stream, W1, w1t);
  hipLaunchKernelGGL(score_gemm, dim3(8, 512), dim3(256), 0, stream, feat, w1t, b1, ph, V, partial);
  hipLaunchKernelGGL(softmax_k, dim3(64), dim3(256), 0, stream, partial, out + 65536);
  hipLaunchKernelGGL(context_k, dim3(8, 64), dim3(256), 0, stream, feat, out + 65536, out);
}

// Round 4
// 783.887 us; speedup vs baseline: 1.1200x; 1.1200x over previous
//
#include <hip/hip_runtime.h>

// ---------------------------------------------------------------------------
// Bahdanau attention, B=64 L=1024 D=H=U=1024, fp32 in/out.
//   score[b,l] = sum_u tanh( (feat@W1)[b,l,u] + b1[u] + (hid@W2)[b,u] + b2[u] ) * V[u]
//   w = softmax_L(score)   (bV dropped: softmax shift-invariant)
//   ctx[b,:] = sum_l w[b,l] * feat[b,l,:]
// R3: feat pre-converted to bf16 in fragment-ordered tiles -> score GEMM is
// pure global_load_lds + conflict-free ds_read_b128 + MFMA. XCD-swizzled grid.
// ---------------------------------------------------------------------------

#define GLD16(g, l) __builtin_amdgcn_global_load_lds(                          \
    (const __attribute__((address_space(1))) void*)(g),                        \
    (__attribute__((address_space(3))) void*)(l), 16, 0, 0)

typedef __attribute__((ext_vector_type(8))) short bf16x8;
typedef __attribute__((ext_vector_type(4))) float f32x4;
typedef __attribute__((ext_vector_type(8))) unsigned short us8;

__device__ __forceinline__ unsigned short f2bf(float f) {
  unsigned u = __float_as_uint(f);  // RNE fp32->bf16
  return (unsigned short)((u + 0x7FFFu + ((u >> 16) & 1u)) >> 16);
}

// K1: ph[b][u] = hidden[b,:] @ W2[:,u] + b2[u].  grid(16,64), 256 thr.
__global__ __launch_bounds__(256) void projh_k(
    const float* __restrict__ hidden, const float* __restrict__ W2,
    const float* __restrict__ b2, float* __restrict__ ph) {
  __shared__ float hs[1024];
  __shared__ float red[4][64];
  const int b = blockIdx.y, ch = blockIdx.x, t = threadIdx.x;
#pragma unroll
  for (int j = 0; j < 4; ++j) hs[t + j * 256] = hidden[b * 1024 + t + j * 256];
  __syncthreads();
  const int ul = t & 63, hq = t >> 6;
  const int u = ch * 64 + ul;
  float acc = 0.f;
#pragma unroll 4
  for (int i = 0; i < 256; ++i) {
    int h = hq * 256 + i;
    acc += hs[h] * W2[(size_t)h * 1024 + u];
  }
  red[hq][ul] = acc;
  __syncthreads();
  if (t < 64) {
    float s = red[0][t] + red[1][t] + red[2][t] + red[3][t] + b2[ch * 64 + t];
    ph[b * 1024 + ch * 64 + t] = s;
  }
}

// ---------------- fragment-ordered fast path -------------------------------
// Tile addressing: chunk index i = ((panel*32 + ks)*8 + mt)*64 + l, 8 bf16 per
// chunk. Lane l = kg*16 + r15 holds row/col (tile*16 + r15), k = ks*32+kg*8+j.
// GEMM stages tile (panel, ks, mt) with one GLD16 per wave-half: LDS gets
// lane-consecutive 16B (conflict-free), and frag reads are lane*16B.

// K2a: W1[d][u] (fp32, row-major) -> w1t fragment-ordered bf16. grid(512),256.
__global__ __launch_bounds__(256) void w1tile_frag_k(
    const float* __restrict__ W1, unsigned short* __restrict__ w1t) {
  const int i = blockIdx.x * 256 + threadIdx.x;  // 131072 chunks
  const int l = i & 63, nt = (i >> 6) & 7, ks = (i >> 9) & 31, nb = i >> 14;
  const int kg = l >> 4, c = l & 15;
  const int u = nb * 128 + nt * 16 + c;
  us8 pk;
#pragma unroll
  for (int j = 0; j < 8; ++j)
    pk[j] = f2bf(W1[(size_t)(ks * 32 + kg * 8 + j) * 1024 + u]);
  *(us8*)(&w1t[(size_t)i * 8]) = pk;
}

// K2b: feat fp32 -> featb fragment-ordered bf16. grid(32768), 256 thr.
__global__ __launch_bounds__(256) void featconv_k(
    const float* __restrict__ feat, unsigned short* __restrict__ featb) {
  const int i = blockIdx.x * 256 + threadIdx.x;  // 8388608 chunks
  const int l = i & 63, mt = (i >> 6) & 7, ks = (i >> 9) & 31, mb = i >> 14;
  const int row = mb * 128 + mt * 16 + (l & 15);
  const int k = ks * 32 + (l >> 4) * 8;
  const float* p = feat + (size_t)row * 1024 + k;
  float4 a = *(const float4*)p;
  float4 b = *(const float4*)(p + 4);
  us8 pk;
  pk[0] = f2bf(a.x); pk[1] = f2bf(a.y); pk[2] = f2bf(a.z); pk[3] = f2bf(a.w);
  pk[4] = f2bf(b.x); pk[5] = f2bf(b.y); pk[6] = f2bf(b.z); pk[7] = f2bf(b.w);
  *(us8*)(&featb[(size_t)i * 8]) = pk;
}

// K3: fused score GEMM (fast path). 128x128 tile, BK=32, 4 waves (2x2),
// 4x4 16x16x32 frags. Both operands via global_load_lds from frag-ordered
// tiles; double-buffered; one barrier per K-step. XCD-swizzled block map:
// nb = by&7, mb = (by>>3)*8 + bx  => the 8 blocks sharing mb have dispatch
// ids congruent mod 8 (same XCD under round-robin) -> feat L2 reuse.
__global__ __launch_bounds__(256) void score_gemm(
    const unsigned short* __restrict__ featb,
    const unsigned short* __restrict__ w1t, const float* __restrict__ b1,
    const float* __restrict__ ph, const float* __restrict__ V,
    float* __restrict__ partial) {
  __shared__ unsigned short As[2][4096];
  __shared__ unsigned short Bs[2][4096];
  __shared__ float phb1_s[128], vs_s[128];
  __shared__ float red2[2][128];

  const int nb = blockIdx.y & 7;
  const int mb = ((blockIdx.y >> 3) << 3) + blockIdx.x;
  const int m_base = mb * 128;
  const int b = m_base >> 10;
  const int tid = threadIdx.x;
  const int lane = tid & 63;
  const int w = tid >> 6, wr = w >> 1, wc = w & 1;

  if (tid < 128) {
    int u = nb * 128 + tid;
    phb1_s[tid] = b1[u] + ph[b * 1024 + u];
    vs_s[tid] = V[u];
  }

  f32x4 acc[4][4];
#pragma unroll
  for (int mi = 0; mi < 4; ++mi)
#pragma unroll
    for (int ni = 0; ni < 4; ++ni) acc[mi][ni] = (f32x4){0.f, 0.f, 0.f, 0.f};

  const unsigned short* Asrc = featb + (size_t)mb * 131072;  // 32 ks * 8 mt * 512
  const unsigned short* Bsrc = w1t + (size_t)nb * 131072;

#define STAGE(ksv, buf)                                                        \
  {                                                                            \
    _Pragma("unroll") for (int p = 0; p < 2; ++p) {                            \
      int mt = w * 2 + p;                                                      \
      GLD16(Asrc + ((size_t)(ksv) * 8 + mt) * 512 + lane * 8,                  \
            &As[buf][mt * 512]);                                               \
      GLD16(Bsrc + ((size_t)(ksv) * 8 + mt) * 512 + lane * 8,                  \
            &Bs[buf][mt * 512]);                                               \
    }                                                                          \
  }

  STAGE(0, 0);
  __syncthreads();

  int cur = 0;
  for (int ks = 0; ks < 32; ++ks) {
    const int nxt = cur ^ 1;
    if (ks + 1 < 32) STAGE(ks + 1, nxt);
    bf16x8 afr[4], bfr[4];
#pragma unroll
    for (int mi = 0; mi < 4; ++mi)
      afr[mi] = *(const bf16x8*)(&As[cur][(wr * 4 + mi) * 512 + lane * 8]);
#pragma unroll
    for (int ni = 0; ni < 4; ++ni)
      bfr[ni] = *(const bf16x8*)(&Bs[cur][(wc * 4 + ni) * 512 + lane * 8]);
#pragma unroll
    for (int mi = 0; mi < 4; ++mi)
#pragma unroll
      for (int ni = 0; ni < 4; ++ni)
        acc[mi][ni] = __builtin_amdgcn_mfma_f32_16x16x32_bf16(
            afr[mi], bfr[ni], acc[mi][ni], 0, 0, 0);
    __syncthreads();
    cur = nxt;
  }
#undef STAGE

  // epilogue: tanh(acc + ph + b1) * V, reduce over this block's 128 u-cols.
  // C/D layout: col = lane&15, row = (lane>>4)*4 + r  [m89-verified]
  float rs[4][4];
#pragma unroll
  for (int mi = 0; mi < 4; ++mi)
#pragma unroll
    for (int r = 0; r < 4; ++r) rs[mi][r] = 0.f;
#pragma unroll
  for (int ni = 0; ni < 4; ++ni) {
    int ucol = wc * 64 + ni * 16 + (lane & 15);
    float pv = phb1_s[ucol], vv = vs_s[ucol];
#pragma unroll
    for (int mi = 0; mi < 4; ++mi)
#pragma unroll
      for (int r = 0; r < 4; ++r)
        rs[mi][r] += tanhf(acc[mi][ni][r] + pv) * vv;
  }
#pragma unroll
  for (int mi = 0; mi < 4; ++mi)
#pragma unroll
    for (int r = 0; r < 4; ++r) {
      float x = rs[mi][r];
      x += __shfl_xor(x, 1);
      x += __shfl_xor(x, 2);
      x += __shfl_xor(x, 4);
      x += __shfl_xor(x, 8);
      rs[mi][r] = x;
    }
  if ((lane & 15) == 0) {
    int rq = lane >> 4;
#pragma unroll
    for (int mi = 0; mi < 4; ++mi)
#pragma unroll
      for (int r = 0; r < 4; ++r)
        red2[wc][wr * 64 + mi * 16 + rq * 4 + r] = rs[mi][r];
  }
  __syncthreads();
  if (tid < 128)
    partial[(size_t)nb * 65536 + m_base + tid] = red2[0][tid] + red2[1][tid];
}

// ---------------- fallback path (round-0, known-passing) -------------------
__global__ __launch_bounds__(256) void w1tile_fb_k(
    const float* __restrict__ W1, unsigned short* __restrict__ w1t) {
  const int i = blockIdx.x * 256 + threadIdx.x;
  const int u = i >> 7, c = i & 127;
  const int ks = c >> 2, kg = c & 3;
  const int col = u & 127, nb = u >> 7;
  us8 pk;
#pragma unroll
  for (int j = 0; j < 8; ++j) {
    int d = ks * 32 + kg * 8 + j;
    pk[j] = f2bf(W1[(size_t)d * 1024 + u]);
  }
  size_t off = (size_t)(nb * 32 + ks) * 4096 + col * 32 +
               ((unsigned)(kg ^ (col & 3)) << 3);
  *(us8*)(&w1t[off]) = pk;
}

__global__ __launch_bounds__(256) void score_fb_k(
    const float* __restrict__ feat, const unsigned short* __restrict__ w1t,
    const float* __restrict__ b1, const float* __restrict__ ph,
    const float* __restrict__ V, float* __restrict__ partial) {
  __shared__ unsigned short As[2][128 * 32];
  __shared__ unsigned short Bs[2][128 * 32];
  __shared__ float phb1_s[128], vs_s[128];
  __shared__ float red2[2][128];
  const int nb = blockIdx.x;
  const int m_base = blockIdx.y * 128;
  const int b = m_base >> 10;
  const int tid = threadIdx.x;
  const int lane = tid & 63;
  const int w = tid >> 6, wr = w >> 1, wc = w & 1;
  if (tid < 128) {
    int u = nb * 128 + tid;
    phb1_s[tid] = b1[u] + ph[b * 1024 + u];
    vs_s[tid] = V[u];
  }
  f32x4 acc[4][4];
#pragma unroll
  for (int mi = 0; mi < 4; ++mi)
#pragma unroll
    for (int ni = 0; ni < 4; ++ni) acc[mi][ni] = (f32x4){0.f, 0.f, 0.f, 0.f};
  const int srow = tid >> 3;
  const int scg = tid & 7;
  const float* fbase = feat + (size_t)m_base * 1024 + scg * 4;
  const unsigned short* wpanel = w1t + (size_t)nb * 131072;
  {
#pragma unroll
    for (int j = 0; j < 2; ++j) {
      int cch = w * 2 + j;
      GLD16(wpanel + cch * 512 + lane * 8, &Bs[0][cch * 512]);
    }
#pragma unroll
    for (int p = 0; p < 4; ++p) {
      int row = p * 32 + srow;
      float4 v = *(const float4*)(fbase + (size_t)row * 1024);
      int off = row * 32 + ((scg * 4) ^ ((row & 3) << 3));
      unsigned a0 = f2bf(v.x) | ((unsigned)f2bf(v.y) << 16);
      unsigned a1 = f2bf(v.z) | ((unsigned)f2bf(v.w) << 16);
      *(uint2*)(&As[0][off]) = make_uint2(a0, a1);
    }
  }
  __syncthreads();
  const int kg = lane >> 4;
  int aoff[4], boff[4];
#pragma unroll
  for (int mi = 0; mi < 4; ++mi) {
    int row = wr * 64 + mi * 16 + (lane & 15);
    aoff[mi] = row * 32 + ((kg * 8) ^ ((row & 3) << 3));
  }
#pragma unroll
  for (int ni = 0; ni < 4; ++ni) {
    int col = wc * 64 + ni * 16 + (lane & 15);
    boff[ni] = col * 32 + ((kg * 8) ^ ((col & 3) << 3));
  }
  int cur = 0;
  for (int ks = 0; ks < 32; ++ks) {
    const int nxt = cur ^ 1;
    const bool more = (ks + 1) < 32;
    float4 av[4];
    if (more) {
      const unsigned short* tsrc = wpanel + (size_t)(ks + 1) * 4096;
#pragma unroll
      for (int j = 0; j < 2; ++j) {
        int cch = w * 2 + j;
        GLD16(tsrc + cch * 512 + lane * 8, &Bs[nxt][cch * 512]);
      }
#pragma unroll
      for (int p = 0; p < 4; ++p) {
        int row = p * 32 + srow;
        av[p] = *(const float4*)(fbase + (size_t)row * 1024 + (ks + 1) * 32);
      }
    }
    bf16x8 afr[4], bfr[4];
#pragma unroll
    for (int mi = 0; mi < 4; ++mi)
      afr[mi] = *(const bf16x8*)(&As[cur][aoff[mi]]);
#pragma unroll
    for (int ni = 0; ni < 4; ++ni)
      bfr[ni] = *(const bf16x8*)(&Bs[cur][boff[ni]]);
#pragma unroll
    for (int mi = 0; mi < 4; ++mi)
#pragma unroll
      for (int ni = 0; ni < 4; ++ni)
        acc[mi][ni] = __builtin_amdgcn_mfma_f32_16x16x32_bf16(
            afr[mi], bfr[ni], acc[mi][ni], 0, 0, 0);
    if (more) {
#pragma unroll
      for (int p = 0; p < 4; ++p) {
        int row = p * 32 + srow;
        int off = row * 32 + ((scg * 4) ^ ((row & 3) << 3));
        unsigned a0 = f2bf(av[p].x) | ((unsigned)f2bf(av[p].y) << 16);
        unsigned a1 = f2bf(av[p].z) | ((unsigned)f2bf(av[p].w) << 16);
        *(uint2*)(&As[nxt][off]) = make_uint2(a0, a1);
      }
    }
    __syncthreads();
    cur = nxt;
  }
  float rs[4][4];
#pragma unroll
  for (int mi = 0; mi < 4; ++mi)
#pragma unroll
    for (int r = 0; r < 4; ++r) rs[mi][r] = 0.f;
#pragma unroll
  for (int ni = 0; ni < 4; ++ni) {
    int ucol = wc * 64 + ni * 16 + (lane & 15);
    float pv = phb1_s[ucol], vv = vs_s[ucol];
#pragma unroll
    for (int mi = 0; mi < 4; ++mi)
#pragma unroll
      for (int r = 0; r < 4; ++r)
        rs[mi][r] += tanhf(acc[mi][ni][r] + pv) * vv;
  }
#pragma unroll
  for (int mi = 0; mi < 4; ++mi)
#pragma unroll
    for (int r = 0; r < 4; ++r) {
      float x = rs[mi][r];
      x += __shfl_xor(x, 1);
      x += __shfl_xor(x, 2);
      x += __shfl_xor(x, 4);
      x += __shfl_xor(x, 8);
      rs[mi][r] = x;
    }
  if ((lane & 15) == 0) {
    int rq = lane >> 4;
#pragma unroll
    for (int mi = 0; mi < 4; ++mi)
#pragma unroll
      for (int r = 0; r < 4; ++r)
        red2[wc][wr * 64 + mi * 16 + rq * 4 + r] = rs[mi][r];
  }
  __syncthreads();
  if (tid < 128)
    partial[(size_t)nb * 65536 + m_base + tid] = red2[0][tid] + red2[1][tid];
}

// K4: softmax over L per b.  grid(64), 256 thr x 4 l each.
__global__ __launch_bounds__(256) void softmax_k(
    const float* __restrict__ partial, float* __restrict__ wout) {
  const int b = blockIdx.x, t = threadIdx.x;
  const int lane = t & 63, w = t >> 6;
  __shared__ float smax[4], ssum[4];
  float s[4];
#pragma unroll
  for (int j = 0; j < 4; ++j) {
    int l = t + j * 256;
    float v = 0.f;
#pragma unroll
    for (int nb = 0; nb < 8; ++nb) v += partial[(size_t)nb * 65536 + b * 1024 + l];
    s[j] = v;
  }
  float mx = fmaxf(fmaxf(s[0], s[1]), fmaxf(s[2], s[3]));
#pragma unroll
  for (int off = 1; off < 64; off <<= 1) mx = fmaxf(mx, __shfl_xor(mx, off));
  if (lane == 0) smax[w] = mx;
  __syncthreads();
  mx = fmaxf(fmaxf(smax[0], smax[1]), fmaxf(smax[2], smax[3]));
  float e[4], sum = 0.f;
#pragma unroll
  for (int j = 0; j < 4; ++j) { e[j] = expf(s[j] - mx); sum += e[j]; }
#pragma unroll
  for (int off = 1; off < 64; off <<= 1) sum += __shfl_xor(sum, off);
  if (lane == 0) ssum[w] = sum;
  __syncthreads();
  const float inv = 1.f / (ssum[0] + ssum[1] + ssum[2] + ssum[3]);
#pragma unroll
  for (int j = 0; j < 4; ++j) wout[b * 1024 + t + j * 256] = e[j] * inv;
}

// K5: ctx[b][d] = sum_l w[b][l] * feat[b][l][d].  grid(8,64), 256 thr.
__global__ __launch_bounds__(256) void context_k(
    const float* __restrict__ feat, const float* __restrict__ wts,
    float* __restrict__ ctx) {
  __shared__ float wsm[1024];
  __shared__ float red[128];
  const int b = blockIdx.y, ch = blockIdx.x, t = threadIdx.x;
#pragma unroll
  for (int j = 0; j < 4; ++j) wsm[t + j * 256] = wts[b * 1024 + t + j * 256];
  __syncthreads();
  const int dl = t & 127, lh = t >> 7;
  const int d = ch * 128 + dl;
  const float* fb = feat + (size_t)b * 1048576 + d;
  float acc = 0.f;
#pragma unroll 4
  for (int l = lh * 512; l < lh * 512 + 512; ++l)
    acc += wsm[l] * fb[(size_t)l * 1024];
  if (lh == 0) red[dl] = acc;
  __syncthreads();
  if (lh == 1) ctx[b * 1024 + d] = red[dl] + acc;
}

extern "C" void kernel_launch(void* const* d_in, const int* in_sizes, int n_in,
                              void* d_out, int out_size, void* d_ws,
                              size_t ws_size, hipStream_t stream) {
  const float* feat = (const float*)d_in[0];    // [64][1024][1024]
  const float* hidden = (const float*)d_in[1];  // [64][1024]
  const float* W1 = (const float*)d_in[2];      // [1024][1024]
  const float* b1 = (const float*)d_in[3];      // [1024]
  const float* W2 = (const float*)d_in[4];      // [1024][1024]
  const float* b2 = (const float*)d_in[5];      // [1024]
  const float* V = (const float*)d_in[6];       // [1024]
  // d_in[7] = bV: unused (softmax shift-invariant)
  float* out = (float*)d_out;  // [0,65536): context  [65536,131072): weights

  // ws layout: ph f32[65536] | partial f32[524288] | w1t bf16[1Mi] | featb bf16[64Mi]
  float* ph = (float*)d_ws;
  float* partial = ph + 65536;
  unsigned short* w1t = (unsigned short*)(partial + 524288);
  unsigned short* featb = w1t + 1048576;
  const size_t need = 4456448ull + 134217728ull;

  hipLaunchKernelGGL(projh_k, dim3(16, 64), dim3(256), 0, stream, hidden, W2, b2, ph);
  if (ws_size >= need) {
    hipLaunchKernelGGL(w1tile_frag_k, dim3(512), dim3(256), 0, stream, W1, w1t);
    hipLaunchKernelGGL(featconv_k, dim3(32768), dim3(256), 0, stream, feat, featb);
    hipLaunchKernelGGL(score_gemm, dim3(8, 512), dim3(256), 0, stream, featb, w1t, b1, ph, V, partial);
  } else {
    hipLaunchKernelGGL(w1tile_fb_k, dim3(512), dim3(256), 0, stream, W1, w1t);
    hipLaunchKernelGGL(score_fb_k, dim3(8, 512), dim3(256), 0, stream, feat, w1t, b1, ph, V, partial);
  }
  hipLaunchKernelGGL(softmax_k, dim3(64), dim3(256), 0, stream, partial, out + 65536);
  hipLaunchKernelGGL(context_k, dim3(8, 64), dim3(256), 0, stream, feat, out + 65536, out);
}